// Round 5
// baseline (812.222 us; speedup 1.0000x reference)
//
#include <hip/hip_runtime.h>
#include <math.h>

#define NB   1152
#define NTOK 64
#define NC   384
#define NH   12
#define NDH  32

typedef short short8 __attribute__((ext_vector_type(8)));
typedef float f32x4  __attribute__((ext_vector_type(4)));

__device__ __forceinline__ unsigned short f2bf(float f) {
    unsigned int u = __builtin_bit_cast(unsigned int, f);
    unsigned int r = u + 0x7fffu + ((u >> 16) & 1u);   // RNE
    return (unsigned short)(r >> 16);
}
__device__ __forceinline__ unsigned int pack2(float lo, float hi) {
    return (unsigned int)f2bf(lo) | ((unsigned int)f2bf(hi) << 16);
}
__device__ __forceinline__ f32x4 mfma_bf16(short8 a, short8 b, f32x4 c) {
    return __builtin_amdgcn_mfma_f32_16x16x32_bf16(a, b, c, 0, 0, 0);
}

// XOR-swizzled 64x384 bf16 tile (no padding, 2-way-free bank pattern).
__device__ __forceinline__ short8 tile_afrag(const unsigned short* t, int row, int kq) {
    return *(const short8*)((const char*)t + row * 768 + ((kq ^ (row & 7)) << 4));
}

// Re-chunk a pair of f32x4 accumulators (lane(Q,t) = [X t][Y 4Q+r], a0: Y 0..15,
// a1: Y 16..31) into an MFMA fragment: lane(Q,t) = [X t][Y 8Q..8Q+7] as bf16x8.
// Validated in R3/R4 (QKV-transposed path).
__device__ __forceinline__ short8 repack_frag(f32x4 a0, f32x4 a1, int Q, int t) {
    unsigned p00 = pack2(a0[0], a0[1]);
    unsigned p01 = pack2(a0[2], a0[3]);
    unsigned p10 = pack2(a1[0], a1[1]);
    unsigned p11 = pack2(a1[2], a1[3]);
    const int s0 = ((Q & 1) << 5) + t;
    const int s1 = s0 + 16;
    int u0a = __shfl((int)p00, s0, 64), u0b = __shfl((int)p10, s0, 64);
    int u1a = __shfl((int)p01, s0, 64), u1b = __shfl((int)p11, s0, 64);
    int u2a = __shfl((int)p00, s1, 64), u2b = __shfl((int)p10, s1, 64);
    int u3a = __shfl((int)p01, s1, 64), u3b = __shfl((int)p11, s1, 64);
    const bool hi = (Q & 2) != 0;
    uint4 u;
    u.x = (unsigned)(hi ? u0b : u0a);
    u.y = (unsigned)(hi ? u1b : u1a);
    u.z = (unsigned)(hi ? u2b : u2a);
    u.w = (unsigned)(hi ? u3b : u3a);
    return __builtin_bit_cast(short8, u);
}

// ---------------------------------------------------------------------------
// prep: transpose+convert weights to bf16 col-major (B-operand layout).
// ---------------------------------------------------------------------------
__global__ __launch_bounds__(256) void prep_kernel(
    const float* __restrict__ wq, const float* __restrict__ wk,
    const float* __restrict__ wv, const float* __restrict__ wproj,
    unsigned int* __restrict__ wT, unsigned int* __restrict__ wprojT)
{
    const int o2 = blockIdx.x * 256 + threadIdx.x;
    if (o2 < 221184) {
        const int col = o2 / 192, k2 = o2 % 192, k = k2 * 2;
        const float* src = (col < 384) ? wq : ((col < 768) ? wk : wv);
        const int c = (col < 384) ? col : ((col < 768) ? col - 384 : col - 768);
        const float a = src[(size_t)k * NC + c];
        const float b = src[(size_t)(k + 1) * NC + c];
        wT[col * 192 + k2] = pack2(a, b);
    } else {
        const int o = o2 - 221184;
        const int col = o / 192, k2 = o % 192, k = k2 * 2;
        const float a = wproj[(size_t)k * NC + col];
        const float b = wproj[(size_t)(k + 1) * NC + col];
        wprojT[col * 192 + k2] = pack2(a, b);
    }
}

// ---------------------------------------------------------------------------
// cpb MLP: 225 blocks x 1 wave.
// ---------------------------------------------------------------------------
__global__ __launch_bounds__(64) void cpb_mlp_kernel(
    const float* __restrict__ w1, const float* __restrict__ b1,
    const float* __restrict__ w2, const float* __restrict__ b2,
    float* __restrict__ tbs)
{
    const int p = blockIdx.x;
    const int lane = threadIdx.x;
    const int ip = p / 15, jp = p % 15;
    float u0 = (float)(jp - 7) * (8.0f / 7.0f);
    float u1 = (float)(ip - 7) * (8.0f / 7.0f);
    float s0 = (u0 > 0.f) ? 1.f : ((u0 < 0.f) ? -1.f : 0.f);
    float s1 = (u1 > 0.f) ? 1.f : ((u1 < 0.f) ? -1.f : 0.f);
    float in0 = s0 * log2f(fabsf(u0) + 1.0f) * (1.0f / 3.0f);
    float in1 = s1 * log2f(fabsf(u1) + 1.0f) * (1.0f / 3.0f);

    float a[12];
    #pragma unroll
    for (int m = 0; m < 12; ++m) a[m] = 0.f;
    #pragma unroll
    for (int e = 0; e < 8; ++e) {
        const int j = lane * 8 + e;
        float hh = fmaxf(in0 * w1[j] + in1 * w1[512 + j] + b1[j], 0.0f);
        #pragma unroll
        for (int m = 0; m < 12; ++m) a[m] += hh * w2[j * 12 + m];
    }
    #pragma unroll
    for (int m = 0; m < 12; ++m) {
        #pragma unroll
        for (int off = 1; off < 64; off <<= 1) a[m] += __shfl_xor(a[m], off, 64);
    }
    if (lane < 12) tbs[p * 12 + lane] = a[lane] + b2[lane];
}

__global__ __launch_bounds__(1024) void bias_gather_kernel(
    const float* __restrict__ tbs, float* __restrict__ bias)
{
    const int i = blockIdx.x * 1024 + threadIdx.x;
    if (i >= NH * NTOK * NTOK) return;
    const int h = i >> 12, rem = i & 4095;
    const int ti = rem >> 6, tj = rem & 63;
    const int dr = (ti >> 3) - (tj >> 3);
    const int dc = (ti & 7) - (tj & 7);
    const int p = (dr + 7) * 15 + (dc + 7);
    bias[i] = 16.0f / (1.0f + __expf(-tbs[p * 12 + h]));
}

// ---------------------------------------------------------------------------
// attn: ONE WAVE = ONE HEAD; LDS = xs ONLY (48 KiB -> 3 blocks/CU).
// 1152 blocks x 256 threads. Wave w owns heads 3w..3w+2, fully independent
// after the single xs barrier. All transposes are repack_frag shuffles:
//   K,Q computed transposed (mfma(w,x)); V computed normal (mfma(x,w)).
//   S computed SWAPPED: sT = mfma(bk, aqf) -> lane(Q,t) = S[q t][k nt*16+4Q+r]
//     => softmax = 16 in-lane + 2 shfl stages; qn, sm lane-local.
//   P->PV B-frag and V->PV A-frag are repack_frag (no Ps/vT LDS, no lgkm
//     round-trip). PV output transposed -> float4 out stores.
// ---------------------------------------------------------------------------
__global__ __launch_bounds__(256, 3) void attn_kernel(
    const float* __restrict__ x,    const float* __restrict__ mask,
    const float* __restrict__ bq,   const float* __restrict__ bv,
    const float* __restrict__ tau,  const unsigned short* __restrict__ wT,
    const float* __restrict__ bias, float* __restrict__ out)
{
    __shared__ unsigned short xs[64 * 384];   // 49152 B — the ONLY LDS

    const int tid  = threadIdx.x;
    const int b    = blockIdx.x;
    const int w    = tid >> 6;      // wave 0..3
    const int lane = tid & 63;
    const int Q    = lane >> 4;     // quad 0..3
    const int t    = lane & 15;     // 0..15

    unsigned int* xsu = (unsigned int*)xs;

    // ---- stage x once: 64 tok x 384 k, fp32 -> bf16, swizzled ----
    {
        const int row = tid >> 2;             // 0..63
        const int q4  = tid & 3;              // 0..3
        const float* xr = &x[((size_t)b * NTOK + row) * NC + q4 * 96];
        #pragma unroll
        for (int e = 0; e < 24; ++e) {
            const float4 xv = *(const float4*)&xr[e * 4];
            const int p = q4 * 48 + e * 2;
            const int g = p >> 2;
            const int u = row * 192 + (((g ^ (row & 7)) << 2) | (p & 3));
            uint2 w2;
            w2.x = pack2(xv.x, xv.y);
            w2.y = pack2(xv.z, xv.w);
            *(uint2*)&xsu[u] = w2;
        }
    }
    __syncthreads();   // the ONLY barrier

    for (int c = 0; c < 3; ++c) {
        const int h = w * 3 + c;

        // ================= PASS 1: K (transposed) + V (normal) =================
        // akv[0..1][tt]: K^T accs: lane(Q,t) = K[tok tt*16+t][dh a*16+4Q+r]
        // akv[2..3][tt]: V accs:   lane(Q,t) = V[tok tt*16+4Q+r][dh n*16+t]
        f32x4 akv[4][4];
        #pragma unroll
        for (int j = 0; j < 4; ++j)
            #pragma unroll
            for (int tt = 0; tt < 4; ++tt) akv[j][tt] = (f32x4){0.f, 0.f, 0.f, 0.f};

        {
            const unsigned short* apk[2];
            const unsigned short* apv[2];
            #pragma unroll
            for (int a = 0; a < 2; ++a) {
                apk[a] = wT + (size_t)(384 + h * 32 + a * 16 + t) * NC + Q * 8;
                apv[a] = wT + (size_t)(768 + h * 32 + a * 16 + t) * NC + Q * 8;
            }
            for (int ks = 0; ks < 12; ++ks) {
                short8 bfr[4];
                #pragma unroll
                for (int tt = 0; tt < 4; ++tt)
                    bfr[tt] = tile_afrag(xs, tt * 16 + t, ks * 4 + Q);
                #pragma unroll
                for (int a = 0; a < 2; ++a) {
                    const short8 afk = *(const short8*)&apk[a][ks * 32];
                    #pragma unroll
                    for (int tt = 0; tt < 4; ++tt)
                        akv[a][tt] = mfma_bf16(afk, bfr[tt], akv[a][tt]);   // K^T
                }
                #pragma unroll
                for (int a = 0; a < 2; ++a) {
                    const short8 afv = *(const short8*)&apv[a][ks * 32];
                    #pragma unroll
                    for (int tt = 0; tt < 4; ++tt)
                        akv[2 + a][tt] = mfma_bf16(bfr[tt], afv, akv[2 + a][tt]); // V
                }
            }
        }

        // ---- V bias (lane's dh = a*16 + t) ----
        #pragma unroll
        for (int a = 0; a < 2; ++a) {
            const float bvv = bv[h * 32 + a * 16 + t];
            #pragma unroll
            for (int tt = 0; tt < 4; ++tt)
                #pragma unroll
                for (int r = 0; r < 4; ++r) akv[2 + a][tt][r] += bvv;
        }

        // ---- k norms (reduce per-lane dh slice across Q) ----
        float kn[4];
        #pragma unroll
        for (int tt = 0; tt < 4; ++tt) {
            float sk = 0.f;
            #pragma unroll
            for (int a = 0; a < 2; ++a)
                #pragma unroll
                for (int r = 0; r < 4; ++r) sk += akv[a][tt][r] * akv[a][tt][r];
            sk += __shfl_xor(sk, 16, 64);
            sk += __shfl_xor(sk, 32, 64);
            kn[tt] = sqrtf(sk);   // lane(·,t): ||k_{tt*16+t}||
        }

        // ---- fragments: K for S (B-op roleless), V^T for PV (A-op) ----
        short8 bk[4];
        #pragma unroll
        for (int nt = 0; nt < 4; ++nt)
            bk[nt] = repack_frag(akv[0][nt], akv[1][nt], Q, t);
        short8 vfrag[2][2];
        #pragma unroll
        for (int n = 0; n < 2; ++n)
            #pragma unroll
            for (int st = 0; st < 2; ++st)
                vfrag[n][st] = repack_frag(akv[2 + n][2 * st], akv[2 + n][2 * st + 1], Q, t);

        // ---- kn broadcast to the (Q,r) axis: knr[nt][r] = ||k_{nt*16+4Q+r}|| ----
        float knr[4][4];
        #pragma unroll
        for (int nt = 0; nt < 4; ++nt)
            #pragma unroll
            for (int r = 0; r < 4; ++r)
                knr[nt][r] = __shfl(kn[nt], Q * 4 + r, 64);

        // ================= PASS 2: Q (transposed) =================
        f32x4 accq[2][4];
        #pragma unroll
        for (int a = 0; a < 2; ++a)
            #pragma unroll
            for (int tt = 0; tt < 4; ++tt) accq[a][tt] = (f32x4){0.f, 0.f, 0.f, 0.f};

        {
            const unsigned short* apq[2];
            #pragma unroll
            for (int a = 0; a < 2; ++a)
                apq[a] = wT + (size_t)(h * 32 + a * 16 + t) * NC + Q * 8;
            for (int ks = 0; ks < 12; ++ks) {
                short8 bfr[4];
                #pragma unroll
                for (int tt = 0; tt < 4; ++tt)
                    bfr[tt] = tile_afrag(xs, tt * 16 + t, ks * 4 + Q);
                #pragma unroll
                for (int a = 0; a < 2; ++a) {
                    const short8 afq = *(const short8*)&apq[a][ks * 32];
                    #pragma unroll
                    for (int tt = 0; tt < 4; ++tt)
                        accq[a][tt] = mfma_bf16(afq, bfr[tt], accq[a][tt]);
                }
            }
        }

        // ---- q bias (lane's dh = a*16 + 4Q + r), norms, fragments ----
        #pragma unroll
        for (int a = 0; a < 2; ++a)
            #pragma unroll
            for (int r = 0; r < 4; ++r) {
                const float bqv = bq[h * 32 + a * 16 + Q * 4 + r];
                #pragma unroll
                for (int tt = 0; tt < 4; ++tt) accq[a][tt][r] += bqv;
            }
        float qn[4];
        short8 aqf[4];
        #pragma unroll
        for (int tt = 0; tt < 4; ++tt) {
            float sq = 0.f;
            #pragma unroll
            for (int a = 0; a < 2; ++a)
                #pragma unroll
                for (int r = 0; r < 4; ++r) sq += accq[a][tt][r] * accq[a][tt][r];
            sq += __shfl_xor(sq, 16, 64);
            sq += __shfl_xor(sq, 32, 64);
            qn[tt] = sqrtf(sq);   // lane(·,t): ||q_{tt*16+t}||  (row-local!)
            aqf[tt] = repack_frag(accq[0][tt], accq[1][tt], Q, t);
        }

        const float ls = fmaxf(tau[h] + 2.302585093f, 0.01f);

        // ================= m-loop: S^T -> softmax -> PV^T -> out =================
        #pragma unroll
        for (int mt = 0; mt < 4; ++mt) {
            // bias+mask, float4 vector loads (row = mt*16+t, cols nt*16+4Q..+3)
            const float* bro = &bias[h * 4096 + (mt * 16 + t) * 64];
            const float* mro = &mask[(size_t)b * 4096 + (mt * 16 + t) * 64];
            f32x4 bm[4];
            #pragma unroll
            for (int nt = 0; nt < 4; ++nt)
                bm[nt] = *(const f32x4*)&bro[nt * 16 + Q * 4]
                       + *(const f32x4*)&mro[nt * 16 + Q * 4];

            // S^T: lane(Q,t) reg r = S[q mt*16+t][k nt*16+4Q+r]
            f32x4 sT[4];
            #pragma unroll
            for (int nt = 0; nt < 4; ++nt)
                sT[nt] = mfma_bf16(bk[nt], aqf[mt], (f32x4){0.f, 0.f, 0.f, 0.f});
            #pragma unroll
            for (int nt = 0; nt < 4; ++nt)
                #pragma unroll
                for (int r = 0; r < 4; ++r) {
                    const float den = fmaxf(qn[mt] * knr[nt][r], 1e-6f);
                    sT[nt][r] = sT[nt][r] / den * ls + bm[nt][r];
                }

            // row softmax: 16 in-lane + 2 cross-Q shfl stages
            float mnt[4];
            #pragma unroll
            for (int nt = 0; nt < 4; ++nt)
                mnt[nt] = fmaxf(fmaxf(sT[nt][0], sT[nt][1]), fmaxf(sT[nt][2], sT[nt][3]));
            float mx = fmaxf(fmaxf(mnt[0], mnt[1]), fmaxf(mnt[2], mnt[3]));
            mx = fmaxf(mx, __shfl_xor(mx, 16, 64));
            mx = fmaxf(mx, __shfl_xor(mx, 32, 64));

            float snt[4];
            #pragma unroll
            for (int nt = 0; nt < 4; ++nt) {
                #pragma unroll
                for (int r = 0; r < 4; ++r) sT[nt][r] = __expf(sT[nt][r] - mx);
                snt[nt] = (sT[nt][0] + sT[nt][1]) + (sT[nt][2] + sT[nt][3]);
            }
            float sm = (snt[0] + snt[1]) + (snt[2] + snt[3]);
            sm += __shfl_xor(sm, 16, 64);
            sm += __shfl_xor(sm, 32, 64);

            // P fragments (B-operand for PV^T): repack along the k axis
            const short8 pf0 = repack_frag(sT[0], sT[1], Q, t);
            const short8 pf1 = repack_frag(sT[2], sT[3], Q, t);

            // O^T = V^T . P^T: lane(Q,t) reg r = O[q mt*16+t][dh n*16+4Q+r]
            f32x4 oa[2];
            oa[0] = (f32x4){0.f, 0.f, 0.f, 0.f};
            oa[1] = (f32x4){0.f, 0.f, 0.f, 0.f};
            #pragma unroll
            for (int n = 0; n < 2; ++n) {
                oa[n] = mfma_bf16(vfrag[n][0], pf0, oa[n]);
                oa[n] = mfma_bf16(vfrag[n][1], pf1, oa[n]);
            }

            const float rsi = 1.0f / sm;
            #pragma unroll
            for (int n = 0; n < 2; ++n) {
                float4 o4;
                o4.x = oa[n][0] * rsi;
                o4.y = oa[n][1] * rsi;
                o4.z = oa[n][2] * rsi;
                o4.w = oa[n][3] * rsi;
                *(float4*)&out[((size_t)b * NTOK + mt * 16 + t) * NC + h * 32 + n * 16 + Q * 4] = o4;
            }
        }
    }
}

// ---------------------------------------------------------------------------
// proj: out = out @ wproj + bproj, in-place. 1152 blocks x 256. (unchanged)
// ---------------------------------------------------------------------------
__global__ __launch_bounds__(256) void proj_kernel(
    const unsigned short* __restrict__ wprojT, const float* __restrict__ bproj,
    float* __restrict__ out)
{
    __shared__ unsigned short as_[64 * 384];
    unsigned int* asu = (unsigned int*)as_;

    const int tid  = threadIdx.x;
    const size_t r0 = (size_t)blockIdx.x * 64;
    const int w    = tid >> 6;
    const int lane = tid & 63;
    const int quad = lane >> 4;
    const int lq   = lane & 15;

    {
        const int row = tid >> 2;
        const int q4  = tid & 3;
        const float* xr = &out[(r0 + row) * NC + q4 * 96];
        #pragma unroll
        for (int e = 0; e < 24; ++e) {
            const float4 xv = *(const float4*)&xr[e * 4];
            const int p = q4 * 48 + e * 2;
            const int g = p >> 2;
            const int u = row * 192 + (((g ^ (row & 7)) << 2) | (p & 3));
            uint2 w2;
            w2.x = pack2(xv.x, xv.y);
            w2.y = pack2(xv.z, xv.w);
            *(uint2*)&asu[u] = w2;
        }
    }
    __syncthreads();

    f32x4 acc[4][6];
    #pragma unroll
    for (int mt = 0; mt < 4; ++mt)
        #pragma unroll
        for (int n = 0; n < 6; ++n) acc[mt][n] = (f32x4){0.f, 0.f, 0.f, 0.f};

    const unsigned short* bp[6];
    #pragma unroll
    for (int n = 0; n < 6; ++n)
        bp[n] = wprojT + (size_t)(w * 96 + n * 16 + lq) * NC + quad * 8;

    for (int ksI = 0; ksI < 12; ++ksI) {
        short8 am[4];
        #pragma unroll
        for (int mt = 0; mt < 4; ++mt)
            am[mt] = tile_afrag(as_, mt * 16 + lq, ksI * 4 + quad);
        #pragma unroll
        for (int n = 0; n < 6; ++n) {
            const short8 bb = *(const short8*)&bp[n][ksI * 32];
            #pragma unroll
            for (int mt = 0; mt < 4; ++mt) acc[mt][n] = mfma_bf16(am[mt], bb, acc[mt][n]);
        }
    }

    float bpv[6];
    #pragma unroll
    for (int n = 0; n < 6; ++n) bpv[n] = bproj[w * 96 + n * 16 + lq];
    #pragma unroll
    for (int mt = 0; mt < 4; ++mt)
        #pragma unroll
        for (int n = 0; n < 6; ++n)
            #pragma unroll
            for (int r = 0; r < 4; ++r)
                out[(r0 + mt * 16 + quad * 4 + r) * NC + w * 96 + n * 16 + lq]
                    = acc[mt][n][r] + bpv[n];
}

// ---------------------------------------------------------------------------
extern "C" void kernel_launch(void* const* d_in, const int* in_sizes, int n_in,
                              void* d_out, int out_size, void* d_ws, size_t ws_size,
                              hipStream_t stream) {
    (void)in_sizes; (void)n_in; (void)out_size; (void)ws_size;
    const float* x     = (const float*)d_in[0];
    const float* mask  = (const float*)d_in[1];
    const float* wq    = (const float*)d_in[2];
    const float* bq    = (const float*)d_in[3];
    const float* wk    = (const float*)d_in[4];
    const float* wv    = (const float*)d_in[5];
    const float* bv    = (const float*)d_in[6];
    const float* w1    = (const float*)d_in[7];
    const float* b1    = (const float*)d_in[8];
    const float* w2    = (const float*)d_in[9];
    const float* b2    = (const float*)d_in[10];
    const float* tau   = (const float*)d_in[11];
    const float* wproj = (const float*)d_in[12];
    const float* bproj = (const float*)d_in[13];
    float* out = (float*)d_out;

    // ws: wT 884736 | wprojT 294912 | bias 196608 | tbs 10800  (~1.39 MB)
    unsigned short* wT     = (unsigned short*)d_ws;
    unsigned short* wprojT = (unsigned short*)((char*)d_ws + 884736);
    float*          bias   = (float*)((char*)d_ws + 884736 + 294912);
    float*          tbs    = (float*)((char*)d_ws + 884736 + 294912 + 196608);

    prep_kernel<<<1152, 256, 0, stream>>>(wq, wk, wv, wproj,
                                          (unsigned int*)wT, (unsigned int*)wprojT);
    cpb_mlp_kernel<<<225, 64, 0, stream>>>(w1, b1, w2, b2, tbs);
    bias_gather_kernel<<<48, 1024, 0, stream>>>(tbs, bias);
    attn_kernel<<<NB, 256, 0, stream>>>(x, mask, bq, bv, tau, wT, bias, out);
    proj_kernel<<<NB, 256, 0, stream>>>(wprojT, bproj, out);
}

// Round 6
// 705.075 us; speedup vs baseline: 1.1520x; 1.1520x over previous
//
#include <hip/hip_runtime.h>
#include <math.h>

#define NB   1152
#define NTOK 64
#define NC   384
#define NH   12
#define NDH  32

typedef short short8 __attribute__((ext_vector_type(8)));
typedef float f32x4  __attribute__((ext_vector_type(4)));

__device__ __forceinline__ unsigned short f2bf(float f) {
    unsigned int u = __builtin_bit_cast(unsigned int, f);
    unsigned int r = u + 0x7fffu + ((u >> 16) & 1u);   // RNE
    return (unsigned short)(r >> 16);
}
__device__ __forceinline__ unsigned int pack2(float lo, float hi) {
    return (unsigned int)f2bf(lo) | ((unsigned int)f2bf(hi) << 16);
}
__device__ __forceinline__ f32x4 mfma_bf16(short8 a, short8 b, f32x4 c) {
    return __builtin_amdgcn_mfma_f32_16x16x32_bf16(a, b, c, 0, 0, 0);
}

// XOR-swizzled 64x384 bf16 tile (no padding, 2-way-free bank pattern).
__device__ __forceinline__ short8 tile_afrag(const unsigned short* t, int row, int kq) {
    return *(const short8*)((const char*)t + row * 768 + ((kq ^ (row & 7)) << 4));
}

// Re-chunk a pair of f32x4 accumulators (lane(Q,t) = [X t][Y 4Q+r], a0: Y 0..15,
// a1: Y 16..31) into an MFMA fragment: lane(Q,t) = [X t][Y 8Q..8Q+7] as bf16x8.
// Validated in R3/R4/R5.
__device__ __forceinline__ short8 repack_frag(f32x4 a0, f32x4 a1, int Q, int t) {
    unsigned p00 = pack2(a0[0], a0[1]);
    unsigned p01 = pack2(a0[2], a0[3]);
    unsigned p10 = pack2(a1[0], a1[1]);
    unsigned p11 = pack2(a1[2], a1[3]);
    const int s0 = ((Q & 1) << 5) + t;
    const int s1 = s0 + 16;
    int u0a = __shfl((int)p00, s0, 64), u0b = __shfl((int)p10, s0, 64);
    int u1a = __shfl((int)p01, s0, 64), u1b = __shfl((int)p11, s0, 64);
    int u2a = __shfl((int)p00, s1, 64), u2b = __shfl((int)p10, s1, 64);
    int u3a = __shfl((int)p01, s1, 64), u3b = __shfl((int)p11, s1, 64);
    const bool hi = (Q & 2) != 0;
    uint4 u;
    u.x = (unsigned)(hi ? u0b : u0a);
    u.y = (unsigned)(hi ? u1b : u1a);
    u.z = (unsigned)(hi ? u2b : u2a);
    u.w = (unsigned)(hi ? u3b : u3a);
    return __builtin_bit_cast(short8, u);
}

// ---------------------------------------------------------------------------
// prep: transpose+convert weights to bf16 col-major (B-operand layout).
// ---------------------------------------------------------------------------
__global__ __launch_bounds__(256) void prep_kernel(
    const float* __restrict__ wq, const float* __restrict__ wk,
    const float* __restrict__ wv, const float* __restrict__ wproj,
    unsigned int* __restrict__ wT, unsigned int* __restrict__ wprojT)
{
    const int o2 = blockIdx.x * 256 + threadIdx.x;
    if (o2 < 221184) {
        const int col = o2 / 192, k2 = o2 % 192, k = k2 * 2;
        const float* src = (col < 384) ? wq : ((col < 768) ? wk : wv);
        const int c = (col < 384) ? col : ((col < 768) ? col - 384 : col - 768);
        const float a = src[(size_t)k * NC + c];
        const float b = src[(size_t)(k + 1) * NC + c];
        wT[col * 192 + k2] = pack2(a, b);
    } else {
        const int o = o2 - 221184;
        const int col = o / 192, k2 = o % 192, k = k2 * 2;
        const float a = wproj[(size_t)k * NC + col];
        const float b = wproj[(size_t)(k + 1) * NC + col];
        wprojT[col * 192 + k2] = pack2(a, b);
    }
}

// ---------------------------------------------------------------------------
// cpb MLP: 225 blocks x 1 wave.
// ---------------------------------------------------------------------------
__global__ __launch_bounds__(64) void cpb_mlp_kernel(
    const float* __restrict__ w1, const float* __restrict__ b1,
    const float* __restrict__ w2, const float* __restrict__ b2,
    float* __restrict__ tbs)
{
    const int p = blockIdx.x;
    const int lane = threadIdx.x;
    const int ip = p / 15, jp = p % 15;
    float u0 = (float)(jp - 7) * (8.0f / 7.0f);
    float u1 = (float)(ip - 7) * (8.0f / 7.0f);
    float s0 = (u0 > 0.f) ? 1.f : ((u0 < 0.f) ? -1.f : 0.f);
    float s1 = (u1 > 0.f) ? 1.f : ((u1 < 0.f) ? -1.f : 0.f);
    float in0 = s0 * log2f(fabsf(u0) + 1.0f) * (1.0f / 3.0f);
    float in1 = s1 * log2f(fabsf(u1) + 1.0f) * (1.0f / 3.0f);

    float a[12];
    #pragma unroll
    for (int m = 0; m < 12; ++m) a[m] = 0.f;
    #pragma unroll
    for (int e = 0; e < 8; ++e) {
        const int j = lane * 8 + e;
        float hh = fmaxf(in0 * w1[j] + in1 * w1[512 + j] + b1[j], 0.0f);
        #pragma unroll
        for (int m = 0; m < 12; ++m) a[m] += hh * w2[j * 12 + m];
    }
    #pragma unroll
    for (int m = 0; m < 12; ++m) {
        #pragma unroll
        for (int off = 1; off < 64; off <<= 1) a[m] += __shfl_xor(a[m], off, 64);
    }
    if (lane < 12) tbs[p * 12 + lane] = a[lane] + b2[lane];
}

__global__ __launch_bounds__(1024) void bias_gather_kernel(
    const float* __restrict__ tbs, float* __restrict__ bias)
{
    const int i = blockIdx.x * 1024 + threadIdx.x;
    if (i >= NH * NTOK * NTOK) return;
    const int h = i >> 12, rem = i & 4095;
    const int ti = rem >> 6, tj = rem & 63;
    const int dr = (ti >> 3) - (tj >> 3);
    const int dc = (ti & 7) - (tj & 7);
    const int p = (dr + 7) * 15 + (dc + 7);
    bias[i] = 16.0f / (1.0f + __expf(-tbs[p * 12 + h]));
}

// ---------------------------------------------------------------------------
// attn: ONE WAVE = ONE HEAD; LDS = xs ONLY (48 KiB -> 3 blocks/CU).
// 1152 blocks x 256 threads. Wave w owns heads 3w..3w+2, fully independent
// after the single xs barrier. All transposes are repack_frag shuffles:
//   K,Q computed transposed (mfma(w,x)); V computed normal (mfma(x,w)).
//   S computed SWAPPED: sT = mfma(bk, aqf) -> lane(Q,t) = S[q t][k nt*16+4Q+r]
//     => softmax = 16 in-lane + 2 shfl stages; qn, sm lane-local.
//   P->PV B-frag and V->PV A-frag are repack_frag (no Ps/vT LDS).
//   PV output transposed -> float4 out stores.
// __launch_bounds__(256, 2) is the ONLY spill-free tier (VGPR=128):
//   (512,4)->64 spilled [R1]; (256,3)->84 spilled 1.1GB [R5]; (256,2)->128
//   clean [R4]. Do not touch.
// ---------------------------------------------------------------------------
__global__ __launch_bounds__(256, 2) void attn_kernel(
    const float* __restrict__ x,    const float* __restrict__ mask,
    const float* __restrict__ bq,   const float* __restrict__ bv,
    const float* __restrict__ tau,  const unsigned short* __restrict__ wT,
    const float* __restrict__ bias, float* __restrict__ out)
{
    __shared__ unsigned short xs[64 * 384];   // 49152 B — the ONLY LDS

    const int tid  = threadIdx.x;
    const int b    = blockIdx.x;
    const int w    = tid >> 6;      // wave 0..3
    const int lane = tid & 63;
    const int Q    = lane >> 4;     // quad 0..3
    const int t    = lane & 15;     // 0..15

    unsigned int* xsu = (unsigned int*)xs;

    // ---- stage x once: 64 tok x 384 k, fp32 -> bf16, swizzled ----
    {
        const int row = tid >> 2;             // 0..63
        const int q4  = tid & 3;              // 0..3
        const float* xr = &x[((size_t)b * NTOK + row) * NC + q4 * 96];
        #pragma unroll
        for (int e = 0; e < 24; ++e) {
            const float4 xv = *(const float4*)&xr[e * 4];
            const int p = q4 * 48 + e * 2;
            const int g = p >> 2;
            const int u = row * 192 + (((g ^ (row & 7)) << 2) | (p & 3));
            uint2 w2;
            w2.x = pack2(xv.x, xv.y);
            w2.y = pack2(xv.z, xv.w);
            *(uint2*)&xsu[u] = w2;
        }
    }
    __syncthreads();   // the ONLY barrier

    for (int c = 0; c < 3; ++c) {
        const int h = w * 3 + c;

        // ================= PASS 1: K (transposed) + V (normal) =================
        // akv[0..1][tt]: K^T accs: lane(Q,t) = K[tok tt*16+t][dh a*16+4Q+r]
        // akv[2..3][tt]: V accs:   lane(Q,t) = V[tok tt*16+4Q+r][dh n*16+t]
        f32x4 akv[4][4];
        #pragma unroll
        for (int j = 0; j < 4; ++j)
            #pragma unroll
            for (int tt = 0; tt < 4; ++tt) akv[j][tt] = (f32x4){0.f, 0.f, 0.f, 0.f};

        {
            const unsigned short* apk[2];
            const unsigned short* apv[2];
            #pragma unroll
            for (int a = 0; a < 2; ++a) {
                apk[a] = wT + (size_t)(384 + h * 32 + a * 16 + t) * NC + Q * 8;
                apv[a] = wT + (size_t)(768 + h * 32 + a * 16 + t) * NC + Q * 8;
            }
            for (int ks = 0; ks < 12; ++ks) {
                short8 bfr[4];
                #pragma unroll
                for (int tt = 0; tt < 4; ++tt)
                    bfr[tt] = tile_afrag(xs, tt * 16 + t, ks * 4 + Q);
                #pragma unroll
                for (int a = 0; a < 2; ++a) {
                    const short8 afk = *(const short8*)&apk[a][ks * 32];
                    #pragma unroll
                    for (int tt = 0; tt < 4; ++tt)
                        akv[a][tt] = mfma_bf16(afk, bfr[tt], akv[a][tt]);   // K^T
                }
                #pragma unroll
                for (int a = 0; a < 2; ++a) {
                    const short8 afv = *(const short8*)&apv[a][ks * 32];
                    #pragma unroll
                    for (int tt = 0; tt < 4; ++tt)
                        akv[2 + a][tt] = mfma_bf16(bfr[tt], afv, akv[2 + a][tt]); // V
                }
            }
        }

        // ---- V bias (lane's dh = a*16 + t) ----
        #pragma unroll
        for (int a = 0; a < 2; ++a) {
            const float bvv = bv[h * 32 + a * 16 + t];
            #pragma unroll
            for (int tt = 0; tt < 4; ++tt)
                #pragma unroll
                for (int r = 0; r < 4; ++r) akv[2 + a][tt][r] += bvv;
        }

        const float ls = fmaxf(tau[h] + 2.302585093f, 0.01f);

        // ---- k norms (reduce per-lane dh slice across Q), folded into ls/kn ----
        float rkn[4];
        #pragma unroll
        for (int tt = 0; tt < 4; ++tt) {
            float sk = 0.f;
            #pragma unroll
            for (int a = 0; a < 2; ++a)
                #pragma unroll
                for (int r = 0; r < 4; ++r) sk += akv[a][tt][r] * akv[a][tt][r];
            sk += __shfl_xor(sk, 16, 64);
            sk += __shfl_xor(sk, 32, 64);
            rkn[tt] = sqrtf(sk);   // lane(·,t): ||k_{tt*16+t}||
        }

        // ---- fragments: K for S, V^T for PV ----
        short8 bk[4];
        #pragma unroll
        for (int nt = 0; nt < 4; ++nt)
            bk[nt] = repack_frag(akv[0][nt], akv[1][nt], Q, t);
        short8 vfrag[2][2];
        #pragma unroll
        for (int n = 0; n < 2; ++n)
            #pragma unroll
            for (int st = 0; st < 2; ++st)
                vfrag[n][st] = repack_frag(akv[2 + n][2 * st], akv[2 + n][2 * st + 1], Q, t);

        // ---- broadcast ls/||k|| to the (Q,r) axis: rknr[nt][r] ----
        float rknr[4][4];
        #pragma unroll
        for (int nt = 0; nt < 4; ++nt) {
            const float lkn = ls / fmaxf(rkn[nt], 1e-30f);
            #pragma unroll
            for (int r = 0; r < 4; ++r)
                rknr[nt][r] = __shfl(lkn, Q * 4 + r, 64);
        }

        // ================= PASS 2: Q (transposed) =================
        f32x4 accq[2][4];
        #pragma unroll
        for (int a = 0; a < 2; ++a)
            #pragma unroll
            for (int tt = 0; tt < 4; ++tt) accq[a][tt] = (f32x4){0.f, 0.f, 0.f, 0.f};

        {
            const unsigned short* apq[2];
            #pragma unroll
            for (int a = 0; a < 2; ++a)
                apq[a] = wT + (size_t)(h * 32 + a * 16 + t) * NC + Q * 8;
            for (int ks = 0; ks < 12; ++ks) {
                short8 bfr[4];
                #pragma unroll
                for (int tt = 0; tt < 4; ++tt)
                    bfr[tt] = tile_afrag(xs, tt * 16 + t, ks * 4 + Q);
                #pragma unroll
                for (int a = 0; a < 2; ++a) {
                    const short8 afq = *(const short8*)&apq[a][ks * 32];
                    #pragma unroll
                    for (int tt = 0; tt < 4; ++tt)
                        accq[a][tt] = mfma_bf16(afq, bfr[tt], accq[a][tt]);
                }
            }
        }

        // ---- q bias (lane's dh = a*16 + 4Q + r), 1/norm, fragments ----
        #pragma unroll
        for (int a = 0; a < 2; ++a)
            #pragma unroll
            for (int r = 0; r < 4; ++r) {
                const float bqv = bq[h * 32 + a * 16 + Q * 4 + r];
                #pragma unroll
                for (int tt = 0; tt < 4; ++tt) accq[a][tt][r] += bqv;
            }
        float rqn[4];
        short8 aqf[4];
        #pragma unroll
        for (int tt = 0; tt < 4; ++tt) {
            float sq = 0.f;
            #pragma unroll
            for (int a = 0; a < 2; ++a)
                #pragma unroll
                for (int r = 0; r < 4; ++r) sq += accq[a][tt][r] * accq[a][tt][r];
            sq += __shfl_xor(sq, 16, 64);
            sq += __shfl_xor(sq, 32, 64);
            rqn[tt] = 1.0f / fmaxf(sqrtf(sq), 1e-30f);  // lane-local 1/||q_row||
            aqf[tt] = repack_frag(accq[0][tt], accq[1][tt], Q, t);
        }

        // ================= m-loop: S^T -> softmax -> PV^T -> out =================
        #pragma unroll
        for (int mt = 0; mt < 4; ++mt) {
            // bias+mask, float4 vector loads (row = mt*16+t, cols nt*16+4Q..+3)
            const float* bro = &bias[h * 4096 + (mt * 16 + t) * 64];
            const float* mro = &mask[(size_t)b * 4096 + (mt * 16 + t) * 64];
            f32x4 bm[4];
            #pragma unroll
            for (int nt = 0; nt < 4; ++nt)
                bm[nt] = *(const f32x4*)&bro[nt * 16 + Q * 4]
                       + *(const f32x4*)&mro[nt * 16 + Q * 4];

            // S^T: lane(Q,t) reg r = S[q mt*16+t][k nt*16+4Q+r]
            f32x4 sT[4];
            #pragma unroll
            for (int nt = 0; nt < 4; ++nt)
                sT[nt] = mfma_bf16(bk[nt], aqf[mt], (f32x4){0.f, 0.f, 0.f, 0.f});
            #pragma unroll
            for (int nt = 0; nt < 4; ++nt)
                #pragma unroll
                for (int r = 0; r < 4; ++r)
                    sT[nt][r] = sT[nt][r] * rqn[mt] * rknr[nt][r] + bm[nt][r];

            // row softmax: 16 in-lane + 2 cross-Q shfl stages
            float mnt[4];
            #pragma unroll
            for (int nt = 0; nt < 4; ++nt)
                mnt[nt] = fmaxf(fmaxf(sT[nt][0], sT[nt][1]), fmaxf(sT[nt][2], sT[nt][3]));
            float mx = fmaxf(fmaxf(mnt[0], mnt[1]), fmaxf(mnt[2], mnt[3]));
            mx = fmaxf(mx, __shfl_xor(mx, 16, 64));
            mx = fmaxf(mx, __shfl_xor(mx, 32, 64));

            float snt[4];
            #pragma unroll
            for (int nt = 0; nt < 4; ++nt) {
                #pragma unroll
                for (int r = 0; r < 4; ++r) sT[nt][r] = __expf(sT[nt][r] - mx);
                snt[nt] = (sT[nt][0] + sT[nt][1]) + (sT[nt][2] + sT[nt][3]);
            }
            float sm = (snt[0] + snt[1]) + (snt[2] + snt[3]);
            sm += __shfl_xor(sm, 16, 64);
            sm += __shfl_xor(sm, 32, 64);

            // P fragments (B-operand for PV^T): repack along the k axis
            const short8 pf0 = repack_frag(sT[0], sT[1], Q, t);
            const short8 pf1 = repack_frag(sT[2], sT[3], Q, t);

            // O^T = V^T . P^T: lane(Q,t) reg r = O[q mt*16+t][dh n*16+4Q+r]
            f32x4 oa[2];
            oa[0] = (f32x4){0.f, 0.f, 0.f, 0.f};
            oa[1] = (f32x4){0.f, 0.f, 0.f, 0.f};
            #pragma unroll
            for (int n = 0; n < 2; ++n) {
                oa[n] = mfma_bf16(vfrag[n][0], pf0, oa[n]);
                oa[n] = mfma_bf16(vfrag[n][1], pf1, oa[n]);
            }

            const float rsi = 1.0f / sm;
            #pragma unroll
            for (int n = 0; n < 2; ++n) {
                float4 o4;
                o4.x = oa[n][0] * rsi;
                o4.y = oa[n][1] * rsi;
                o4.z = oa[n][2] * rsi;
                o4.w = oa[n][3] * rsi;
                *(float4*)&out[((size_t)b * NTOK + mt * 16 + t) * NC + h * 32 + n * 16 + Q * 4] = o4;
            }
        }
    }
}

// ---------------------------------------------------------------------------
// proj: out = out @ wproj + bproj, in-place. 1152 blocks x 256. (unchanged)
// ---------------------------------------------------------------------------
__global__ __launch_bounds__(256) void proj_kernel(
    const unsigned short* __restrict__ wprojT, const float* __restrict__ bproj,
    float* __restrict__ out)
{
    __shared__ unsigned short as_[64 * 384];
    unsigned int* asu = (unsigned int*)as_;

    const int tid  = threadIdx.x;
    const size_t r0 = (size_t)blockIdx.x * 64;
    const int w    = tid >> 6;
    const int lane = tid & 63;
    const int quad = lane >> 4;
    const int lq   = lane & 15;

    {
        const int row = tid >> 2;
        const int q4  = tid & 3;
        const float* xr = &out[(r0 + row) * NC + q4 * 96];
        #pragma unroll
        for (int e = 0; e < 24; ++e) {
            const float4 xv = *(const float4*)&xr[e * 4];
            const int p = q4 * 48 + e * 2;
            const int g = p >> 2;
            const int u = row * 192 + (((g ^ (row & 7)) << 2) | (p & 3));
            uint2 w2;
            w2.x = pack2(xv.x, xv.y);
            w2.y = pack2(xv.z, xv.w);
            *(uint2*)&asu[u] = w2;
        }
    }
    __syncthreads();

    f32x4 acc[4][6];
    #pragma unroll
    for (int mt = 0; mt < 4; ++mt)
        #pragma unroll
        for (int n = 0; n < 6; ++n) acc[mt][n] = (f32x4){0.f, 0.f, 0.f, 0.f};

    const unsigned short* bp[6];
    #pragma unroll
    for (int n = 0; n < 6; ++n)
        bp[n] = wprojT + (size_t)(w * 96 + n * 16 + lq) * NC + quad * 8;

    for (int ksI = 0; ksI < 12; ++ksI) {
        short8 am[4];
        #pragma unroll
        for (int mt = 0; mt < 4; ++mt)
            am[mt] = tile_afrag(as_, mt * 16 + lq, ksI * 4 + quad);
        #pragma unroll
        for (int n = 0; n < 6; ++n) {
            const short8 bb = *(const short8*)&bp[n][ksI * 32];
            #pragma unroll
            for (int mt = 0; mt < 4; ++mt) acc[mt][n] = mfma_bf16(am[mt], bb, acc[mt][n]);
        }
    }

    float bpv[6];
    #pragma unroll
    for (int n = 0; n < 6; ++n) bpv[n] = bproj[w * 96 + n * 16 + lq];
    #pragma unroll
    for (int mt = 0; mt < 4; ++mt)
        #pragma unroll
        for (int n = 0; n < 6; ++n)
            #pragma unroll
            for (int r = 0; r < 4; ++r)
                out[(r0 + mt * 16 + quad * 4 + r) * NC + w * 96 + n * 16 + lq]
                    = acc[mt][n][r] + bpv[n];
}

// ---------------------------------------------------------------------------
extern "C" void kernel_launch(void* const* d_in, const int* in_sizes, int n_in,
                              void* d_out, int out_size, void* d_ws, size_t ws_size,
                              hipStream_t stream) {
    (void)in_sizes; (void)n_in; (void)out_size; (void)ws_size;
    const float* x     = (const float*)d_in[0];
    const float* mask  = (const float*)d_in[1];
    const float* wq    = (const float*)d_in[2];
    const float* bq    = (const float*)d_in[3];
    const float* wk    = (const float*)d_in[4];
    const float* wv    = (const float*)d_in[5];
    const float* bv    = (const float*)d_in[6];
    const float* w1    = (const float*)d_in[7];
    const float* b1    = (const float*)d_in[8];
    const float* w2    = (const float*)d_in[9];
    const float* b2    = (const float*)d_in[10];
    const float* tau   = (const float*)d_in[11];
    const float* wproj = (const float*)d_in[12];
    const float* bproj = (const float*)d_in[13];
    float* out = (float*)d_out;

    // ws: wT 884736 | wprojT 294912 | bias 196608 | tbs 10800  (~1.39 MB)
    unsigned short* wT     = (unsigned short*)d_ws;
    unsigned short* wprojT = (unsigned short*)((char*)d_ws + 884736);
    float*          bias   = (float*)((char*)d_ws + 884736 + 294912);
    float*          tbs    = (float*)((char*)d_ws + 884736 + 294912 + 196608);

    prep_kernel<<<1152, 256, 0, stream>>>(wq, wk, wv, wproj,
                                          (unsigned int*)wT, (unsigned int*)wprojT);
    cpb_mlp_kernel<<<225, 64, 0, stream>>>(w1, b1, w2, b2, tbs);
    bias_gather_kernel<<<48, 1024, 0, stream>>>(tbs, bias);
    attn_kernel<<<NB, 256, 0, stream>>>(x, mask, bq, bv, tau, wT, bias, out);
    proj_kernel<<<NB, 256, 0, stream>>>(wprojT, bproj, out);
}

// Round 7
// 704.092 us; speedup vs baseline: 1.1536x; 1.0014x over previous
//
#include <hip/hip_runtime.h>
#include <math.h>

#define NB   1152
#define NTOK 64
#define NC   384
#define NH   12
#define NDH  32

typedef short short8 __attribute__((ext_vector_type(8)));
typedef float f32x4  __attribute__((ext_vector_type(4)));

__device__ __forceinline__ unsigned short f2bf(float f) {
    unsigned int u = __builtin_bit_cast(unsigned int, f);
    unsigned int r = u + 0x7fffu + ((u >> 16) & 1u);   // RNE
    return (unsigned short)(r >> 16);
}
__device__ __forceinline__ unsigned int pack2(float lo, float hi) {
    return (unsigned int)f2bf(lo) | ((unsigned int)f2bf(hi) << 16);
}
__device__ __forceinline__ f32x4 mfma_bf16(short8 a, short8 b, f32x4 c) {
    return __builtin_amdgcn_mfma_f32_16x16x32_bf16(a, b, c, 0, 0, 0);
}

// XOR-swizzled 64x384 bf16 tile (no padding, 2-way-free bank pattern).
__device__ __forceinline__ short8 tile_afrag(const unsigned short* t, int row, int kq) {
    return *(const short8*)((const char*)t + row * 768 + ((kq ^ (row & 7)) << 4));
}

// Re-chunk a pair of f32x4 accumulators (lane(Q,t) = [X t][Y 4Q+r], a0: Y 0..15,
// a1: Y 16..31) into an MFMA fragment: lane(Q,t) = [X t][Y 8Q..8Q+7] as bf16x8.
// Validated in R3..R6.
__device__ __forceinline__ short8 repack_frag(f32x4 a0, f32x4 a1, int Q, int t) {
    unsigned p00 = pack2(a0[0], a0[1]);
    unsigned p01 = pack2(a0[2], a0[3]);
    unsigned p10 = pack2(a1[0], a1[1]);
    unsigned p11 = pack2(a1[2], a1[3]);
    const int s0 = ((Q & 1) << 5) + t;
    const int s1 = s0 + 16;
    int u0a = __shfl((int)p00, s0, 64), u0b = __shfl((int)p10, s0, 64);
    int u1a = __shfl((int)p01, s0, 64), u1b = __shfl((int)p11, s0, 64);
    int u2a = __shfl((int)p00, s1, 64), u2b = __shfl((int)p10, s1, 64);
    int u3a = __shfl((int)p01, s1, 64), u3b = __shfl((int)p11, s1, 64);
    const bool hi = (Q & 2) != 0;
    uint4 u;
    u.x = (unsigned)(hi ? u0b : u0a);
    u.y = (unsigned)(hi ? u1b : u1a);
    u.z = (unsigned)(hi ? u2b : u2a);
    u.w = (unsigned)(hi ? u3b : u3a);
    return __builtin_bit_cast(short8, u);
}

// ---------------------------------------------------------------------------
// prep: transpose+convert weights to bf16 col-major (B-operand layout).
// ---------------------------------------------------------------------------
__global__ __launch_bounds__(256) void prep_kernel(
    const float* __restrict__ wq, const float* __restrict__ wk,
    const float* __restrict__ wv, const float* __restrict__ wproj,
    unsigned int* __restrict__ wT, unsigned int* __restrict__ wprojT)
{
    const int o2 = blockIdx.x * 256 + threadIdx.x;
    if (o2 < 221184) {
        const int col = o2 / 192, k2 = o2 % 192, k = k2 * 2;
        const float* src = (col < 384) ? wq : ((col < 768) ? wk : wv);
        const int c = (col < 384) ? col : ((col < 768) ? col - 384 : col - 768);
        const float a = src[(size_t)k * NC + c];
        const float b = src[(size_t)(k + 1) * NC + c];
        wT[col * 192 + k2] = pack2(a, b);
    } else {
        const int o = o2 - 221184;
        const int col = o / 192, k2 = o % 192, k = k2 * 2;
        const float a = wproj[(size_t)k * NC + col];
        const float b = wproj[(size_t)(k + 1) * NC + col];
        wprojT[col * 192 + k2] = pack2(a, b);
    }
}

// ---------------------------------------------------------------------------
// cpb MLP: 225 blocks x 1 wave.
// ---------------------------------------------------------------------------
__global__ __launch_bounds__(64) void cpb_mlp_kernel(
    const float* __restrict__ w1, const float* __restrict__ b1,
    const float* __restrict__ w2, const float* __restrict__ b2,
    float* __restrict__ tbs)
{
    const int p = blockIdx.x;
    const int lane = threadIdx.x;
    const int ip = p / 15, jp = p % 15;
    float u0 = (float)(jp - 7) * (8.0f / 7.0f);
    float u1 = (float)(ip - 7) * (8.0f / 7.0f);
    float s0 = (u0 > 0.f) ? 1.f : ((u0 < 0.f) ? -1.f : 0.f);
    float s1 = (u1 > 0.f) ? 1.f : ((u1 < 0.f) ? -1.f : 0.f);
    float in0 = s0 * log2f(fabsf(u0) + 1.0f) * (1.0f / 3.0f);
    float in1 = s1 * log2f(fabsf(u1) + 1.0f) * (1.0f / 3.0f);

    float a[12];
    #pragma unroll
    for (int m = 0; m < 12; ++m) a[m] = 0.f;
    #pragma unroll
    for (int e = 0; e < 8; ++e) {
        const int j = lane * 8 + e;
        float hh = fmaxf(in0 * w1[j] + in1 * w1[512 + j] + b1[j], 0.0f);
        #pragma unroll
        for (int m = 0; m < 12; ++m) a[m] += hh * w2[j * 12 + m];
    }
    #pragma unroll
    for (int m = 0; m < 12; ++m) {
        #pragma unroll
        for (int off = 1; off < 64; off <<= 1) a[m] += __shfl_xor(a[m], off, 64);
    }
    if (lane < 12) tbs[p * 12 + lane] = a[lane] + b2[lane];
}

__global__ __launch_bounds__(1024) void bias_gather_kernel(
    const float* __restrict__ tbs, float* __restrict__ bias)
{
    const int i = blockIdx.x * 1024 + threadIdx.x;
    if (i >= NH * NTOK * NTOK) return;
    const int h = i >> 12, rem = i & 4095;
    const int ti = rem >> 6, tj = rem & 63;
    const int dr = (ti >> 3) - (tj >> 3);
    const int dc = (ti & 7) - (tj & 7);
    const int p = (dr + 7) * 15 + (dc + 7);
    bias[i] = 16.0f / (1.0f + __expf(-tbs[p * 12 + h]));
}

// ---------------------------------------------------------------------------
// attn: ONE WAVE = ONE HEAD; LDS = xs ONLY (48 KiB -> 3 blocks/CU).
// 1152 blocks x 256 threads. Wave w owns heads 3w..3w+2, fully independent
// after the single xs barrier. All transposes are repack_frag shuffles.
// COSINE NORMS FOLDED INTO FRAGMENTS (R7): q-accs scaled by ls/||q|| and
// k-accs by 1/||k|| BEFORE the bf16 repack (both lane-local in the
// transposed layout). S^T = mfma(bk, aqf, C=bias+mask) -- no rknr[16]/rqn[4]
// registers, no broadcast shuffles, no scale pass. This removes the ~20-reg
// overshoot that spilled ~350MB of scratch traffic in R6.
// __launch_bounds__(256, 2) is the ONLY spill-free tier (VGPR=128):
//   (512,4)->64 [R1], (256,3)->84 [R5] both spilled; do not touch.
// ---------------------------------------------------------------------------
__global__ __launch_bounds__(256, 2) void attn_kernel(
    const float* __restrict__ x,    const float* __restrict__ mask,
    const float* __restrict__ bq,   const float* __restrict__ bv,
    const float* __restrict__ tau,  const unsigned short* __restrict__ wT,
    const float* __restrict__ bias, float* __restrict__ out)
{
    __shared__ unsigned short xs[64 * 384];   // 49152 B — the ONLY LDS

    const int tid  = threadIdx.x;
    const int b    = blockIdx.x;
    const int w    = tid >> 6;      // wave 0..3
    const int lane = tid & 63;
    const int Q    = lane >> 4;     // quad 0..3
    const int t    = lane & 15;     // 0..15

    unsigned int* xsu = (unsigned int*)xs;

    // ---- stage x once: 64 tok x 384 k, fp32 -> bf16, swizzled ----
    {
        const int row = tid >> 2;             // 0..63
        const int q4  = tid & 3;              // 0..3
        const float* xr = &x[((size_t)b * NTOK + row) * NC + q4 * 96];
        #pragma unroll
        for (int e = 0; e < 24; ++e) {
            const float4 xv = *(const float4*)&xr[e * 4];
            const int p = q4 * 48 + e * 2;
            const int g = p >> 2;
            const int u = row * 192 + (((g ^ (row & 7)) << 2) | (p & 3));
            uint2 w2;
            w2.x = pack2(xv.x, xv.y);
            w2.y = pack2(xv.z, xv.w);
            *(uint2*)&xsu[u] = w2;
        }
    }
    __syncthreads();   // the ONLY barrier

    for (int c = 0; c < 3; ++c) {
        const int h = w * 3 + c;

        // ================= PASS 1: K (transposed) + V (normal) =================
        // akv[0..1][tt]: K^T accs: lane(Q,t) = K[tok tt*16+t][dh a*16+4Q+r]
        // akv[2..3][tt]: V accs:   lane(Q,t) = V[tok tt*16+4Q+r][dh n*16+t]
        f32x4 akv[4][4];
        #pragma unroll
        for (int j = 0; j < 4; ++j)
            #pragma unroll
            for (int tt = 0; tt < 4; ++tt) akv[j][tt] = (f32x4){0.f, 0.f, 0.f, 0.f};

        {
            const unsigned short* apk[2];
            const unsigned short* apv[2];
            #pragma unroll
            for (int a = 0; a < 2; ++a) {
                apk[a] = wT + (size_t)(384 + h * 32 + a * 16 + t) * NC + Q * 8;
                apv[a] = wT + (size_t)(768 + h * 32 + a * 16 + t) * NC + Q * 8;
            }
            for (int ks = 0; ks < 12; ++ks) {
                short8 bfr[4];
                #pragma unroll
                for (int tt = 0; tt < 4; ++tt)
                    bfr[tt] = tile_afrag(xs, tt * 16 + t, ks * 4 + Q);
                #pragma unroll
                for (int a = 0; a < 2; ++a) {
                    const short8 afk = *(const short8*)&apk[a][ks * 32];
                    #pragma unroll
                    for (int tt = 0; tt < 4; ++tt)
                        akv[a][tt] = mfma_bf16(afk, bfr[tt], akv[a][tt]);   // K^T
                }
                #pragma unroll
                for (int a = 0; a < 2; ++a) {
                    const short8 afv = *(const short8*)&apv[a][ks * 32];
                    #pragma unroll
                    for (int tt = 0; tt < 4; ++tt)
                        akv[2 + a][tt] = mfma_bf16(bfr[tt], afv, akv[2 + a][tt]); // V
                }
            }
        }

        // ---- V bias (lane's dh = a*16 + t) ----
        #pragma unroll
        for (int a = 0; a < 2; ++a) {
            const float bvv = bv[h * 32 + a * 16 + t];
            #pragma unroll
            for (int tt = 0; tt < 4; ++tt)
                #pragma unroll
                for (int r = 0; r < 4; ++r) akv[2 + a][tt][r] += bvv;
        }

        const float ls = fmaxf(tau[h] + 2.302585093f, 0.01f);

        // ---- k norms folded into k accs: akv[0..1] *= 1/||k|| (lane-local) ----
        #pragma unroll
        for (int tt = 0; tt < 4; ++tt) {
            float sk = 0.f;
            #pragma unroll
            for (int a = 0; a < 2; ++a)
                #pragma unroll
                for (int r = 0; r < 4; ++r) sk += akv[a][tt][r] * akv[a][tt][r];
            sk += __shfl_xor(sk, 16, 64);
            sk += __shfl_xor(sk, 32, 64);
            const float rk = 1.0f / fmaxf(sqrtf(sk), 1e-3f);
            #pragma unroll
            for (int a = 0; a < 2; ++a)
                #pragma unroll
                for (int r = 0; r < 4; ++r) akv[a][tt][r] *= rk;
        }

        // ---- fragments: K̂ for S, V^T for PV ----
        short8 bk[4];
        #pragma unroll
        for (int nt = 0; nt < 4; ++nt)
            bk[nt] = repack_frag(akv[0][nt], akv[1][nt], Q, t);
        short8 vfrag[2][2];
        #pragma unroll
        for (int n = 0; n < 2; ++n)
            #pragma unroll
            for (int st = 0; st < 2; ++st)
                vfrag[n][st] = repack_frag(akv[2 + n][2 * st], akv[2 + n][2 * st + 1], Q, t);

        // ================= PASS 2: Q (transposed) =================
        f32x4 accq[2][4];
        #pragma unroll
        for (int a = 0; a < 2; ++a)
            #pragma unroll
            for (int tt = 0; tt < 4; ++tt) accq[a][tt] = (f32x4){0.f, 0.f, 0.f, 0.f};

        {
            const unsigned short* apq[2];
            #pragma unroll
            for (int a = 0; a < 2; ++a)
                apq[a] = wT + (size_t)(h * 32 + a * 16 + t) * NC + Q * 8;
            for (int ks = 0; ks < 12; ++ks) {
                short8 bfr[4];
                #pragma unroll
                for (int tt = 0; tt < 4; ++tt)
                    bfr[tt] = tile_afrag(xs, tt * 16 + t, ks * 4 + Q);
                #pragma unroll
                for (int a = 0; a < 2; ++a) {
                    const short8 afq = *(const short8*)&apq[a][ks * 32];
                    #pragma unroll
                    for (int tt = 0; tt < 4; ++tt)
                        accq[a][tt] = mfma_bf16(afq, bfr[tt], accq[a][tt]);
                }
            }
        }

        // ---- q bias + ls/||q|| folded into q accs (lane-local), fragments ----
        #pragma unroll
        for (int a = 0; a < 2; ++a)
            #pragma unroll
            for (int r = 0; r < 4; ++r) {
                const float bqv = bq[h * 32 + a * 16 + Q * 4 + r];
                #pragma unroll
                for (int tt = 0; tt < 4; ++tt) accq[a][tt][r] += bqv;
            }
        short8 aqf[4];
        #pragma unroll
        for (int tt = 0; tt < 4; ++tt) {
            float sq = 0.f;
            #pragma unroll
            for (int a = 0; a < 2; ++a)
                #pragma unroll
                for (int r = 0; r < 4; ++r) sq += accq[a][tt][r] * accq[a][tt][r];
            sq += __shfl_xor(sq, 16, 64);
            sq += __shfl_xor(sq, 32, 64);
            const float lq_ = ls / fmaxf(sqrtf(sq), 1e-3f);
            #pragma unroll
            for (int a = 0; a < 2; ++a)
                #pragma unroll
                for (int r = 0; r < 4; ++r) accq[a][tt][r] *= lq_;
            aqf[tt] = repack_frag(accq[0][tt], accq[1][tt], Q, t);
        }

        // ================= m-loop: S^T -> softmax -> PV^T -> out =================
        #pragma unroll
        for (int mt = 0; mt < 4; ++mt) {
            // bias+mask, float4 vector loads (row = mt*16+t, cols nt*16+4Q..+3)
            const float* bro = &bias[h * 4096 + (mt * 16 + t) * 64];
            const float* mro = &mask[(size_t)b * 4096 + (mt * 16 + t) * 64];
            f32x4 bm[4];
            #pragma unroll
            for (int nt = 0; nt < 4; ++nt)
                bm[nt] = *(const f32x4*)&bro[nt * 16 + Q * 4]
                       + *(const f32x4*)&mro[nt * 16 + Q * 4];

            // S^T: lane(Q,t) reg r = S[q mt*16+t][k nt*16+4Q+r]
            // (cosine scale pre-folded; bias+mask ride the MFMA C-operand)
            f32x4 sT[4];
            #pragma unroll
            for (int nt = 0; nt < 4; ++nt)
                sT[nt] = mfma_bf16(bk[nt], aqf[mt], bm[nt]);

            // row softmax: 16 in-lane + 2 cross-Q shfl stages
            float mnt[4];
            #pragma unroll
            for (int nt = 0; nt < 4; ++nt)
                mnt[nt] = fmaxf(fmaxf(sT[nt][0], sT[nt][1]), fmaxf(sT[nt][2], sT[nt][3]));
            float mx = fmaxf(fmaxf(mnt[0], mnt[1]), fmaxf(mnt[2], mnt[3]));
            mx = fmaxf(mx, __shfl_xor(mx, 16, 64));
            mx = fmaxf(mx, __shfl_xor(mx, 32, 64));

            float snt[4];
            #pragma unroll
            for (int nt = 0; nt < 4; ++nt) {
                #pragma unroll
                for (int r = 0; r < 4; ++r) sT[nt][r] = __expf(sT[nt][r] - mx);
                snt[nt] = (sT[nt][0] + sT[nt][1]) + (sT[nt][2] + sT[nt][3]);
            }
            float sm = (snt[0] + snt[1]) + (snt[2] + snt[3]);
            sm += __shfl_xor(sm, 16, 64);
            sm += __shfl_xor(sm, 32, 64);

            // P fragments (B-operand for PV^T): repack along the k axis
            const short8 pf0 = repack_frag(sT[0], sT[1], Q, t);
            const short8 pf1 = repack_frag(sT[2], sT[3], Q, t);

            // O^T = V^T . P^T: lane(Q,t) reg r = O[q mt*16+t][dh n*16+4Q+r]
            f32x4 oa[2];
            oa[0] = (f32x4){0.f, 0.f, 0.f, 0.f};
            oa[1] = (f32x4){0.f, 0.f, 0.f, 0.f};
            #pragma unroll
            for (int n = 0; n < 2; ++n) {
                oa[n] = mfma_bf16(vfrag[n][0], pf0, oa[n]);
                oa[n] = mfma_bf16(vfrag[n][1], pf1, oa[n]);
            }

            const float rsi = 1.0f / sm;
            #pragma unroll
            for (int n = 0; n < 2; ++n) {
                float4 o4;
                o4.x = oa[n][0] * rsi;
                o4.y = oa[n][1] * rsi;
                o4.z = oa[n][2] * rsi;
                o4.w = oa[n][3] * rsi;
                *(float4*)&out[((size_t)b * NTOK + mt * 16 + t) * NC + h * 32 + n * 16 + Q * 4] = o4;
            }
        }
    }
}

// ---------------------------------------------------------------------------
// proj: out = out @ wproj + bproj, in-place. 1152 blocks x 256. (unchanged)
// ---------------------------------------------------------------------------
__global__ __launch_bounds__(256) void proj_kernel(
    const unsigned short* __restrict__ wprojT, const float* __restrict__ bproj,
    float* __restrict__ out)
{
    __shared__ unsigned short as_[64 * 384];
    unsigned int* asu = (unsigned int*)as_;

    const int tid  = threadIdx.x;
    const size_t r0 = (size_t)blockIdx.x * 64;
    const int w    = tid >> 6;
    const int lane = tid & 63;
    const int quad = lane >> 4;
    const int lq   = lane & 15;

    {
        const int row = tid >> 2;
        const int q4  = tid & 3;
        const float* xr = &out[(r0 + row) * NC + q4 * 96];
        #pragma unroll
        for (int e = 0; e < 24; ++e) {
            const float4 xv = *(const float4*)&xr[e * 4];
            const int p = q4 * 48 + e * 2;
            const int g = p >> 2;
            const int u = row * 192 + (((g ^ (row & 7)) << 2) | (p & 3));
            uint2 w2;
            w2.x = pack2(xv.x, xv.y);
            w2.y = pack2(xv.z, xv.w);
            *(uint2*)&asu[u] = w2;
        }
    }
    __syncthreads();

    f32x4 acc[4][6];
    #pragma unroll
    for (int mt = 0; mt < 4; ++mt)
        #pragma unroll
        for (int n = 0; n < 6; ++n) acc[mt][n] = (f32x4){0.f, 0.f, 0.f, 0.f};

    const unsigned short* bp[6];
    #pragma unroll
    for (int n = 0; n < 6; ++n)
        bp[n] = wprojT + (size_t)(w * 96 + n * 16 + lq) * NC + quad * 8;

    for (int ksI = 0; ksI < 12; ++ksI) {
        short8 am[4];
        #pragma unroll
        for (int mt = 0; mt < 4; ++mt)
            am[mt] = tile_afrag(as_, mt * 16 + lq, ksI * 4 + quad);
        #pragma unroll
        for (int n = 0; n < 6; ++n) {
            const short8 bb = *(const short8*)&bp[n][ksI * 32];
            #pragma unroll
            for (int mt = 0; mt < 4; ++mt) acc[mt][n] = mfma_bf16(am[mt], bb, acc[mt][n]);
        }
    }

    float bpv[6];
    #pragma unroll
    for (int n = 0; n < 6; ++n) bpv[n] = bproj[w * 96 + n * 16 + lq];
    #pragma unroll
    for (int mt = 0; mt < 4; ++mt)
        #pragma unroll
        for (int n = 0; n < 6; ++n)
            #pragma unroll
            for (int r = 0; r < 4; ++r)
                out[(r0 + mt * 16 + quad * 4 + r) * NC + w * 96 + n * 16 + lq]
                    = acc[mt][n][r] + bpv[n];
}

// ---------------------------------------------------------------------------
extern "C" void kernel_launch(void* const* d_in, const int* in_sizes, int n_in,
                              void* d_out, int out_size, void* d_ws, size_t ws_size,
                              hipStream_t stream) {
    (void)in_sizes; (void)n_in; (void)out_size; (void)ws_size;
    const float* x     = (const float*)d_in[0];
    const float* mask  = (const float*)d_in[1];
    const float* wq    = (const float*)d_in[2];
    const float* bq    = (const float*)d_in[3];
    const float* wk    = (const float*)d_in[4];
    const float* wv    = (const float*)d_in[5];
    const float* bv    = (const float*)d_in[6];
    const float* w1    = (const float*)d_in[7];
    const float* b1    = (const float*)d_in[8];
    const float* w2    = (const float*)d_in[9];
    const float* b2    = (const float*)d_in[10];
    const float* tau   = (const float*)d_in[11];
    const float* wproj = (const float*)d_in[12];
    const float* bproj = (const float*)d_in[13];
    float* out = (float*)d_out;

    // ws: wT 884736 | wprojT 294912 | bias 196608 | tbs 10800  (~1.39 MB)
    unsigned short* wT     = (unsigned short*)d_ws;
    unsigned short* wprojT = (unsigned short*)((char*)d_ws + 884736);
    float*          bias   = (float*)((char*)d_ws + 884736 + 294912);
    float*          tbs    = (float*)((char*)d_ws + 884736 + 294912 + 196608);

    prep_kernel<<<1152, 256, 0, stream>>>(wq, wk, wv, wproj,
                                          (unsigned int*)wT, (unsigned int*)wprojT);
    cpb_mlp_kernel<<<225, 64, 0, stream>>>(w1, b1, w2, b2, tbs);
    bias_gather_kernel<<<48, 1024, 0, stream>>>(tbs, bias);
    attn_kernel<<<NB, 256, 0, stream>>>(x, mask, bq, bv, tau, wT, bias, out);
    proj_kernel<<<NB, 256, 0, stream>>>(wprojT, bproj, out);
}

// Round 8
// 679.271 us; speedup vs baseline: 1.1957x; 1.0365x over previous
//
#include <hip/hip_runtime.h>
#include <math.h>

#define NB   1152
#define NTOK 64
#define NC   384
#define NH   12
#define NDH  32

typedef short short8 __attribute__((ext_vector_type(8)));
typedef float f32x4  __attribute__((ext_vector_type(4)));

__device__ __forceinline__ unsigned short f2bf(float f) {
    unsigned int u = __builtin_bit_cast(unsigned int, f);
    unsigned int r = u + 0x7fffu + ((u >> 16) & 1u);   // RNE
    return (unsigned short)(r >> 16);
}
__device__ __forceinline__ unsigned int pack2(float lo, float hi) {
    return (unsigned int)f2bf(lo) | ((unsigned int)f2bf(hi) << 16);
}
__device__ __forceinline__ f32x4 mfma_bf16(short8 a, short8 b, f32x4 c) {
    return __builtin_amdgcn_mfma_f32_16x16x32_bf16(a, b, c, 0, 0, 0);
}

// XOR-swizzled 64x384 bf16 tile (no padding, 2-way-free bank pattern).
__device__ __forceinline__ short8 tile_afrag(const unsigned short* t, int row, int kq) {
    return *(const short8*)((const char*)t + row * 768 + ((kq ^ (row & 7)) << 4));
}

// Re-chunk a pair of f32x4 accumulators (lane(Q,t) = [X t][Y 4Q+r], a0: Y 0..15,
// a1: Y 16..31) into an MFMA fragment: lane(Q,t) = [X t][Y 8Q..8Q+7] as bf16x8.
// Validated in R3..R7.
__device__ __forceinline__ short8 repack_frag(f32x4 a0, f32x4 a1, int Q, int t) {
    unsigned p00 = pack2(a0[0], a0[1]);
    unsigned p01 = pack2(a0[2], a0[3]);
    unsigned p10 = pack2(a1[0], a1[1]);
    unsigned p11 = pack2(a1[2], a1[3]);
    const int s0 = ((Q & 1) << 5) + t;
    const int s1 = s0 + 16;
    int u0a = __shfl((int)p00, s0, 64), u0b = __shfl((int)p10, s0, 64);
    int u1a = __shfl((int)p01, s0, 64), u1b = __shfl((int)p11, s0, 64);
    int u2a = __shfl((int)p00, s1, 64), u2b = __shfl((int)p10, s1, 64);
    int u3a = __shfl((int)p01, s1, 64), u3b = __shfl((int)p11, s1, 64);
    const bool hi = (Q & 2) != 0;
    uint4 u;
    u.x = (unsigned)(hi ? u0b : u0a);
    u.y = (unsigned)(hi ? u1b : u1a);
    u.z = (unsigned)(hi ? u2b : u2a);
    u.w = (unsigned)(hi ? u3b : u3a);
    return __builtin_bit_cast(short8, u);
}

// ---------------------------------------------------------------------------
// prep: transpose+convert weights to bf16 col-major (B-operand layout).
// ---------------------------------------------------------------------------
__global__ __launch_bounds__(256) void prep_kernel(
    const float* __restrict__ wq, const float* __restrict__ wk,
    const float* __restrict__ wv, const float* __restrict__ wproj,
    unsigned int* __restrict__ wT, unsigned int* __restrict__ wprojT)
{
    const int o2 = blockIdx.x * 256 + threadIdx.x;
    if (o2 < 221184) {
        const int col = o2 / 192, k2 = o2 % 192, k = k2 * 2;
        const float* src = (col < 384) ? wq : ((col < 768) ? wk : wv);
        const int c = (col < 384) ? col : ((col < 768) ? col - 384 : col - 768);
        const float a = src[(size_t)k * NC + c];
        const float b = src[(size_t)(k + 1) * NC + c];
        wT[col * 192 + k2] = pack2(a, b);
    } else {
        const int o = o2 - 221184;
        const int col = o / 192, k2 = o % 192, k = k2 * 2;
        const float a = wproj[(size_t)k * NC + col];
        const float b = wproj[(size_t)(k + 1) * NC + col];
        wprojT[col * 192 + k2] = pack2(a, b);
    }
}

// ---------------------------------------------------------------------------
// cpb MLP: 225 blocks x 1 wave.
// ---------------------------------------------------------------------------
__global__ __launch_bounds__(64) void cpb_mlp_kernel(
    const float* __restrict__ w1, const float* __restrict__ b1,
    const float* __restrict__ w2, const float* __restrict__ b2,
    float* __restrict__ tbs)
{
    const int p = blockIdx.x;
    const int lane = threadIdx.x;
    const int ip = p / 15, jp = p % 15;
    float u0 = (float)(jp - 7) * (8.0f / 7.0f);
    float u1 = (float)(ip - 7) * (8.0f / 7.0f);
    float s0 = (u0 > 0.f) ? 1.f : ((u0 < 0.f) ? -1.f : 0.f);
    float s1 = (u1 > 0.f) ? 1.f : ((u1 < 0.f) ? -1.f : 0.f);
    float in0 = s0 * log2f(fabsf(u0) + 1.0f) * (1.0f / 3.0f);
    float in1 = s1 * log2f(fabsf(u1) + 1.0f) * (1.0f / 3.0f);

    float a[12];
    #pragma unroll
    for (int m = 0; m < 12; ++m) a[m] = 0.f;
    #pragma unroll
    for (int e = 0; e < 8; ++e) {
        const int j = lane * 8 + e;
        float hh = fmaxf(in0 * w1[j] + in1 * w1[512 + j] + b1[j], 0.0f);
        #pragma unroll
        for (int m = 0; m < 12; ++m) a[m] += hh * w2[j * 12 + m];
    }
    #pragma unroll
    for (int m = 0; m < 12; ++m) {
        #pragma unroll
        for (int off = 1; off < 64; off <<= 1) a[m] += __shfl_xor(a[m], off, 64);
    }
    if (lane < 12) tbs[p * 12 + lane] = a[lane] + b2[lane];
}

__global__ __launch_bounds__(1024) void bias_gather_kernel(
    const float* __restrict__ tbs, float* __restrict__ bias)
{
    const int i = blockIdx.x * 1024 + threadIdx.x;
    if (i >= NH * NTOK * NTOK) return;
    const int h = i >> 12, rem = i & 4095;
    const int ti = rem >> 6, tj = rem & 63;
    const int dr = (ti >> 3) - (tj >> 3);
    const int dc = (ti & 7) - (tj & 7);
    const int p = (dr + 7) * 15 + (dc + 7);
    bias[i] = 16.0f / (1.0f + __expf(-tbs[p * 12 + h]));
}

// ---------------------------------------------------------------------------
// attn: ONE WAVE = ONE HEAD; LDS = xs ONLY (48 KiB -> 3 blocks/CU).
// 1152 blocks x 256 threads. Wave w owns heads 3w..3w+2, fully independent
// after the single xs barrier. All transposes are repack_frag shuffles.
// Cosine norms folded into fragments (R7). S^T = mfma(bk, aqf, C=bias+mask).
//
// REGISTER POLICY (R8): plain __launch_bounds__(256) -- NO min-waves arg.
// Evidence across the session: any 2nd arg makes hipcc spill-to-fit a hard
// VGPR cap ((512,4)->64, (256,3)->84, (256,2)->128; all spilled: symmetric
// FETCH/WRITE excess 0.3-1.1 GB). Plain (256) allocates need-based (R0: 88,
// clean 77/110 MB). Peak live here ~145 -> expect ~145-180 VGPR, 0 spill.
// ---------------------------------------------------------------------------
__global__ __launch_bounds__(256) void attn_kernel(
    const float* __restrict__ x,    const float* __restrict__ mask,
    const float* __restrict__ bq,   const float* __restrict__ bv,
    const float* __restrict__ tau,  const unsigned short* __restrict__ wT,
    const float* __restrict__ bias, float* __restrict__ out)
{
    __shared__ unsigned short xs[64 * 384];   // 49152 B — the ONLY LDS

    const int tid  = threadIdx.x;
    const int b    = blockIdx.x;
    const int w    = tid >> 6;      // wave 0..3
    const int lane = tid & 63;
    const int Q    = lane >> 4;     // quad 0..3
    const int t    = lane & 15;     // 0..15

    unsigned int* xsu = (unsigned int*)xs;

    // ---- stage x once: 64 tok x 384 k, fp32 -> bf16, swizzled ----
    {
        const int row = tid >> 2;             // 0..63
        const int q4  = tid & 3;              // 0..3
        const float* xr = &x[((size_t)b * NTOK + row) * NC + q4 * 96];
        #pragma unroll
        for (int e = 0; e < 24; ++e) {
            const float4 xv = *(const float4*)&xr[e * 4];
            const int p = q4 * 48 + e * 2;
            const int g = p >> 2;
            const int u = row * 192 + (((g ^ (row & 7)) << 2) | (p & 3));
            uint2 w2;
            w2.x = pack2(xv.x, xv.y);
            w2.y = pack2(xv.z, xv.w);
            *(uint2*)&xsu[u] = w2;
        }
    }
    __syncthreads();   // the ONLY barrier

    for (int c = 0; c < 3; ++c) {
        const int h = w * 3 + c;

        // ================= PASS 1: K (transposed) + V (normal) =================
        // akv[0..1][tt]: K^T accs: lane(Q,t) = K[tok tt*16+t][dh a*16+4Q+r]
        // akv[2..3][tt]: V accs:   lane(Q,t) = V[tok tt*16+4Q+r][dh n*16+t]
        f32x4 akv[4][4];
        #pragma unroll
        for (int j = 0; j < 4; ++j)
            #pragma unroll
            for (int tt = 0; tt < 4; ++tt) akv[j][tt] = (f32x4){0.f, 0.f, 0.f, 0.f};

        {
            const unsigned short* apk[2];
            const unsigned short* apv[2];
            #pragma unroll
            for (int a = 0; a < 2; ++a) {
                apk[a] = wT + (size_t)(384 + h * 32 + a * 16 + t) * NC + Q * 8;
                apv[a] = wT + (size_t)(768 + h * 32 + a * 16 + t) * NC + Q * 8;
            }
            for (int ks = 0; ks < 12; ++ks) {
                short8 bfr[4];
                #pragma unroll
                for (int tt = 0; tt < 4; ++tt)
                    bfr[tt] = tile_afrag(xs, tt * 16 + t, ks * 4 + Q);
                #pragma unroll
                for (int a = 0; a < 2; ++a) {
                    const short8 afk = *(const short8*)&apk[a][ks * 32];
                    #pragma unroll
                    for (int tt = 0; tt < 4; ++tt)
                        akv[a][tt] = mfma_bf16(afk, bfr[tt], akv[a][tt]);   // K^T
                }
                #pragma unroll
                for (int a = 0; a < 2; ++a) {
                    const short8 afv = *(const short8*)&apv[a][ks * 32];
                    #pragma unroll
                    for (int tt = 0; tt < 4; ++tt)
                        akv[2 + a][tt] = mfma_bf16(bfr[tt], afv, akv[2 + a][tt]); // V
                }
            }
        }

        // ---- V bias (lane's dh = a*16 + t) ----
        #pragma unroll
        for (int a = 0; a < 2; ++a) {
            const float bvv = bv[h * 32 + a * 16 + t];
            #pragma unroll
            for (int tt = 0; tt < 4; ++tt)
                #pragma unroll
                for (int r = 0; r < 4; ++r) akv[2 + a][tt][r] += bvv;
        }

        const float ls = fmaxf(tau[h] + 2.302585093f, 0.01f);

        // ---- k norms folded into k accs: akv[0..1] *= 1/||k|| (lane-local) ----
        #pragma unroll
        for (int tt = 0; tt < 4; ++tt) {
            float sk = 0.f;
            #pragma unroll
            for (int a = 0; a < 2; ++a)
                #pragma unroll
                for (int r = 0; r < 4; ++r) sk += akv[a][tt][r] * akv[a][tt][r];
            sk += __shfl_xor(sk, 16, 64);
            sk += __shfl_xor(sk, 32, 64);
            const float rk = 1.0f / fmaxf(sqrtf(sk), 1e-3f);
            #pragma unroll
            for (int a = 0; a < 2; ++a)
                #pragma unroll
                for (int r = 0; r < 4; ++r) akv[a][tt][r] *= rk;
        }

        // ---- fragments: K̂ for S, V^T for PV ----
        short8 bk[4];
        #pragma unroll
        for (int nt = 0; nt < 4; ++nt)
            bk[nt] = repack_frag(akv[0][nt], akv[1][nt], Q, t);
        short8 vfrag[2][2];
        #pragma unroll
        for (int n = 0; n < 2; ++n)
            #pragma unroll
            for (int st = 0; st < 2; ++st)
                vfrag[n][st] = repack_frag(akv[2 + n][2 * st], akv[2 + n][2 * st + 1], Q, t);

        // ================= PASS 2: Q (transposed) =================
        f32x4 accq[2][4];
        #pragma unroll
        for (int a = 0; a < 2; ++a)
            #pragma unroll
            for (int tt = 0; tt < 4; ++tt) accq[a][tt] = (f32x4){0.f, 0.f, 0.f, 0.f};

        {
            const unsigned short* apq[2];
            #pragma unroll
            for (int a = 0; a < 2; ++a)
                apq[a] = wT + (size_t)(h * 32 + a * 16 + t) * NC + Q * 8;
            for (int ks = 0; ks < 12; ++ks) {
                short8 bfr[4];
                #pragma unroll
                for (int tt = 0; tt < 4; ++tt)
                    bfr[tt] = tile_afrag(xs, tt * 16 + t, ks * 4 + Q);
                #pragma unroll
                for (int a = 0; a < 2; ++a) {
                    const short8 afq = *(const short8*)&apq[a][ks * 32];
                    #pragma unroll
                    for (int tt = 0; tt < 4; ++tt)
                        accq[a][tt] = mfma_bf16(afq, bfr[tt], accq[a][tt]);
                }
            }
        }

        // ---- q bias + ls/||q|| folded into q accs (lane-local), fragments ----
        #pragma unroll
        for (int a = 0; a < 2; ++a)
            #pragma unroll
            for (int r = 0; r < 4; ++r) {
                const float bqv = bq[h * 32 + a * 16 + Q * 4 + r];
                #pragma unroll
                for (int tt = 0; tt < 4; ++tt) accq[a][tt][r] += bqv;
            }
        short8 aqf[4];
        #pragma unroll
        for (int tt = 0; tt < 4; ++tt) {
            float sq = 0.f;
            #pragma unroll
            for (int a = 0; a < 2; ++a)
                #pragma unroll
                for (int r = 0; r < 4; ++r) sq += accq[a][tt][r] * accq[a][tt][r];
            sq += __shfl_xor(sq, 16, 64);
            sq += __shfl_xor(sq, 32, 64);
            const float lq_ = ls / fmaxf(sqrtf(sq), 1e-3f);
            #pragma unroll
            for (int a = 0; a < 2; ++a)
                #pragma unroll
                for (int r = 0; r < 4; ++r) accq[a][tt][r] *= lq_;
            aqf[tt] = repack_frag(accq[0][tt], accq[1][tt], Q, t);
        }

        // ================= m-loop: S^T -> softmax -> PV^T -> out =================
        #pragma unroll
        for (int mt = 0; mt < 4; ++mt) {
            // bias+mask, float4 vector loads (row = mt*16+t, cols nt*16+4Q..+3)
            const float* bro = &bias[h * 4096 + (mt * 16 + t) * 64];
            const float* mro = &mask[(size_t)b * 4096 + (mt * 16 + t) * 64];
            f32x4 bm[4];
            #pragma unroll
            for (int nt = 0; nt < 4; ++nt)
                bm[nt] = *(const f32x4*)&bro[nt * 16 + Q * 4]
                       + *(const f32x4*)&mro[nt * 16 + Q * 4];

            // S^T: lane(Q,t) reg r = S[q mt*16+t][k nt*16+4Q+r]
            // (cosine scale pre-folded; bias+mask ride the MFMA C-operand)
            f32x4 sT[4];
            #pragma unroll
            for (int nt = 0; nt < 4; ++nt)
                sT[nt] = mfma_bf16(bk[nt], aqf[mt], bm[nt]);

            // row softmax: 16 in-lane + 2 cross-Q shfl stages
            float mnt[4];
            #pragma unroll
            for (int nt = 0; nt < 4; ++nt)
                mnt[nt] = fmaxf(fmaxf(sT[nt][0], sT[nt][1]), fmaxf(sT[nt][2], sT[nt][3]));
            float mx = fmaxf(fmaxf(mnt[0], mnt[1]), fmaxf(mnt[2], mnt[3]));
            mx = fmaxf(mx, __shfl_xor(mx, 16, 64));
            mx = fmaxf(mx, __shfl_xor(mx, 32, 64));

            float snt[4];
            #pragma unroll
            for (int nt = 0; nt < 4; ++nt) {
                #pragma unroll
                for (int r = 0; r < 4; ++r) sT[nt][r] = __expf(sT[nt][r] - mx);
                snt[nt] = (sT[nt][0] + sT[nt][1]) + (sT[nt][2] + sT[nt][3]);
            }
            float sm = (snt[0] + snt[1]) + (snt[2] + snt[3]);
            sm += __shfl_xor(sm, 16, 64);
            sm += __shfl_xor(sm, 32, 64);

            // P fragments (B-operand for PV^T): repack along the k axis
            const short8 pf0 = repack_frag(sT[0], sT[1], Q, t);
            const short8 pf1 = repack_frag(sT[2], sT[3], Q, t);

            // O^T = V^T . P^T: lane(Q,t) reg r = O[q mt*16+t][dh n*16+4Q+r]
            f32x4 oa[2];
            oa[0] = (f32x4){0.f, 0.f, 0.f, 0.f};
            oa[1] = (f32x4){0.f, 0.f, 0.f, 0.f};
            #pragma unroll
            for (int n = 0; n < 2; ++n) {
                oa[n] = mfma_bf16(vfrag[n][0], pf0, oa[n]);
                oa[n] = mfma_bf16(vfrag[n][1], pf1, oa[n]);
            }

            const float rsi = 1.0f / sm;
            #pragma unroll
            for (int n = 0; n < 2; ++n) {
                float4 o4;
                o4.x = oa[n][0] * rsi;
                o4.y = oa[n][1] * rsi;
                o4.z = oa[n][2] * rsi;
                o4.w = oa[n][3] * rsi;
                *(float4*)&out[((size_t)b * NTOK + mt * 16 + t) * NC + h * 32 + n * 16 + Q * 4] = o4;
            }
        }
    }
}

// ---------------------------------------------------------------------------
// proj: out = out @ wproj + bproj, in-place. 1152 blocks x 256. (unchanged)
// ---------------------------------------------------------------------------
__global__ __launch_bounds__(256) void proj_kernel(
    const unsigned short* __restrict__ wprojT, const float* __restrict__ bproj,
    float* __restrict__ out)
{
    __shared__ unsigned short as_[64 * 384];
    unsigned int* asu = (unsigned int*)as_;

    const int tid  = threadIdx.x;
    const size_t r0 = (size_t)blockIdx.x * 64;
    const int w    = tid >> 6;
    const int lane = tid & 63;
    const int quad = lane >> 4;
    const int lq   = lane & 15;

    {
        const int row = tid >> 2;
        const int q4  = tid & 3;
        const float* xr = &out[(r0 + row) * NC + q4 * 96];
        #pragma unroll
        for (int e = 0; e < 24; ++e) {
            const float4 xv = *(const float4*)&xr[e * 4];
            const int p = q4 * 48 + e * 2;
            const int g = p >> 2;
            const int u = row * 192 + (((g ^ (row & 7)) << 2) | (p & 3));
            uint2 w2;
            w2.x = pack2(xv.x, xv.y);
            w2.y = pack2(xv.z, xv.w);
            *(uint2*)&asu[u] = w2;
        }
    }
    __syncthreads();

    f32x4 acc[4][6];
    #pragma unroll
    for (int mt = 0; mt < 4; ++mt)
        #pragma unroll
        for (int n = 0; n < 6; ++n) acc[mt][n] = (f32x4){0.f, 0.f, 0.f, 0.f};

    const unsigned short* bp[6];
    #pragma unroll
    for (int n = 0; n < 6; ++n)
        bp[n] = wprojT + (size_t)(w * 96 + n * 16 + lq) * NC + quad * 8;

    for (int ksI = 0; ksI < 12; ++ksI) {
        short8 am[4];
        #pragma unroll
        for (int mt = 0; mt < 4; ++mt)
            am[mt] = tile_afrag(as_, mt * 16 + lq, ksI * 4 + quad);
        #pragma unroll
        for (int n = 0; n < 6; ++n) {
            const short8 bb = *(const short8*)&bp[n][ksI * 32];
            #pragma unroll
            for (int mt = 0; mt < 4; ++mt) acc[mt][n] = mfma_bf16(am[mt], bb, acc[mt][n]);
        }
    }

    float bpv[6];
    #pragma unroll
    for (int n = 0; n < 6; ++n) bpv[n] = bproj[w * 96 + n * 16 + lq];
    #pragma unroll
    for (int mt = 0; mt < 4; ++mt)
        #pragma unroll
        for (int n = 0; n < 6; ++n)
            #pragma unroll
            for (int r = 0; r < 4; ++r)
                out[(r0 + mt * 16 + quad * 4 + r) * NC + w * 96 + n * 16 + lq]
                    = acc[mt][n][r] + bpv[n];
}

// ---------------------------------------------------------------------------
extern "C" void kernel_launch(void* const* d_in, const int* in_sizes, int n_in,
                              void* d_out, int out_size, void* d_ws, size_t ws_size,
                              hipStream_t stream) {
    (void)in_sizes; (void)n_in; (void)out_size; (void)ws_size;
    const float* x     = (const float*)d_in[0];
    const float* mask  = (const float*)d_in[1];
    const float* wq    = (const float*)d_in[2];
    const float* bq    = (const float*)d_in[3];
    const float* wk    = (const float*)d_in[4];
    const float* wv    = (const float*)d_in[5];
    const float* bv    = (const float*)d_in[6];
    const float* w1    = (const float*)d_in[7];
    const float* b1    = (const float*)d_in[8];
    const float* w2    = (const float*)d_in[9];
    const float* b2    = (const float*)d_in[10];
    const float* tau   = (const float*)d_in[11];
    const float* wproj = (const float*)d_in[12];
    const float* bproj = (const float*)d_in[13];
    float* out = (float*)d_out;

    // ws: wT 884736 | wprojT 294912 | bias 196608 | tbs 10800  (~1.39 MB)
    unsigned short* wT     = (unsigned short*)d_ws;
    unsigned short* wprojT = (unsigned short*)((char*)d_ws + 884736);
    float*          bias   = (float*)((char*)d_ws + 884736 + 294912);
    float*          tbs    = (float*)((char*)d_ws + 884736 + 294912 + 196608);

    prep_kernel<<<1152, 256, 0, stream>>>(wq, wk, wv, wproj,
                                          (unsigned int*)wT, (unsigned int*)wprojT);
    cpb_mlp_kernel<<<225, 64, 0, stream>>>(w1, b1, w2, b2, tbs);
    bias_gather_kernel<<<48, 1024, 0, stream>>>(tbs, bias);
    attn_kernel<<<NB, 256, 0, stream>>>(x, mask, bq, bv, tau, wT, bias, out);
    proj_kernel<<<NB, 256, 0, stream>>>(wprojT, bproj, out);
}